// Round 7
// baseline (211.982 us; speedup 1.0000x reference)
//
#include <hip/hip_runtime.h>

typedef __attribute__((ext_vector_type(8))) short short8_t;  // 8 bf16 (4 VGPRs)
typedef __attribute__((ext_vector_type(4))) float float4_t;  // MFMA C/D
typedef __attribute__((ext_vector_type(8))) _Float16 half8_t;
typedef unsigned short u16;
typedef unsigned int u32;
typedef unsigned long long u64;

// ---------- helpers ----------
__device__ inline u16 f2bf(float x) {
  union { float f; u32 u; } v; v.f = x;
  u32 r = v.u + 0x7FFFu + ((v.u >> 16) & 1u);  // round-to-nearest-even
  return (u16)(r >> 16);
}
#if __has_builtin(__builtin_amdgcn_cvt_pk_bf16_f32)
typedef __attribute__((ext_vector_type(2))) __bf16 bf162_t;
__device__ inline u32 pk2(float a, float b) {   // v_cvt_pk_bf16_f32: low=a, high=b, RNE
  union { bf162_t v; u32 u; } cv;
  cv.v = __builtin_amdgcn_cvt_pk_bf16_f32(a, b);
  return cv.u;
}
#else
__device__ inline u32 pk2(float a, float b) {
  return (u32)f2bf(a) | ((u32)f2bf(b) << 16);
}
#endif

// ---------- fused prologue: X fp32->bf16 (blocks 0..4095), W transposes (4096..8191),
// ---------- per-batch all-ones mask flags (8192..8193, only when flags != null) ----------
__global__ __launch_bounds__(256) void prologue(const float* __restrict__ X,
                                                const float* __restrict__ Wq, const float* __restrict__ Wk,
                                                const float* __restrict__ Wv, const float* __restrict__ Wo,
                                                u16* __restrict__ Xb, u16* __restrict__ WqkvT,
                                                u16* __restrict__ WoT, const float* __restrict__ maskp,
                                                u32* __restrict__ flags) {
  __shared__ float tls[32][33];
  int bid = blockIdx.x;
  if (bid < 4096) {
    int i = bid * 256 + threadIdx.x;  // one float4 per thread
    float4_t x = ((const float4_t*)X)[i];
    union { u32 u[2]; u64 ll; } o;
    o.u[0] = pk2(x[0], x[1]);
    o.u[1] = pk2(x[2], x[3]);
    ((u64*)Xb)[i] = o.ll;
  } else if (bid < 8192) {
    int t = bid - 4096;
    int mat = t >> 10, tile = t & 1023;
    const float* W = (mat == 0) ? Wq : (mat == 1) ? Wk : (mat == 2) ? Wv : Wo;
    u16* WT = (mat < 3) ? WqkvT + ((size_t)mat << 20) : WoT;
    int tx = threadIdx.x & 31, ty = threadIdx.x >> 5;  // 32 x 8
    int c0 = (tile & 31) * 32, r0 = (tile >> 5) * 32;  // r0: k, c0: n
    #pragma unroll
    for (int i = 0; i < 4; ++i)
      tls[ty + i * 8][tx] = W[(r0 + ty + i * 8) * 1024 + c0 + tx];
    __syncthreads();
    #pragma unroll
    for (int i = 0; i < 4; ++i)
      WT[(size_t)(c0 + ty + i * 8) * 1024 + r0 + tx] = f2bf(tls[tx][ty + i * 8]);
  } else {
    // all-ones detection for attention mask, one block per batch
    int b = bid - 8192;
    const float* mb = maskp + (b << 11) + threadIdx.x * 8;
    bool ok = true;
    #pragma unroll
    for (int i = 0; i < 8; ++i) ok &= (mb[i] == 1.0f);
    u64 bal = __ballot(ok);
    int w = threadIdx.x >> 6;
    if ((threadIdx.x & 63) == 0) tls[0][w] = (bal == ~0ull) ? 1.0f : 0.0f;
    __syncthreads();
    if (threadIdx.x == 0)
      flags[b] = (tls[0][0] != 0.0f && tls[0][1] != 0.0f &&
                  tls[0][2] != 0.0f && tls[0][3] != 0.0f) ? 1u : 0u;
  }
}

// combined-Ctx row loader for the O-proj GEMM (mode 3): rows s<1024 come from bf16
// Ctx; rows s>=1024 are split-K partials (fp16 O1,O2 + fp32 l1,l2 in the dead
// Xb/WqkvT workspace) combined on the fly: (O1+O2)/(l1+l2). Branch is wave-uniform
// (128-row GEMM bands align with the 1024 boundary).
__device__ inline short8_t load_ctx_row(const u16* __restrict__ A, int r, int col0,
                                        const u16* __restrict__ Op1h, const u16* __restrict__ Op2h,
                                        const float* __restrict__ lp1, const float* __restrict__ lp2) {
  if (!(r & 1024))
    return *(const short8_t*)(A + (size_t)r * 1024 + col0);
  int b = r >> 11, s = r & 2047;
  int hh = col0 >> 6, d0 = col0 & 63;   // k0 is 64-aligned -> head = col0>>6
  int qt = s >> 6, jj = 31 - qt, q = s & 63;
  int slot = (((b << 4) + hh) << 4) + jj;
  size_t off = ((size_t)slot * 64 + q) * 64 + d0;
  half8_t o1 = *(const half8_t*)(Op1h + off);
  half8_t o2 = *(const half8_t*)(Op2h + off);
  float rl = 1.0f / (lp1[slot * 64 + q] + lp2[slot * 64 + q]);
  union { u32 u[4]; short8_t v; } ov;
  #pragma unroll
  for (int e = 0; e < 4; ++e)
    ov.u[e] = pk2(((float)o1[2 * e] + (float)o2[2 * e]) * rl,
                  ((float)o1[2 * e + 1] + (float)o2[2 * e + 1]) * rl);
  return ov.v;
}

// ---------- GEMM: 128x128 C-tile, 4 waves each 64x64, BK=64, VGPR-pipelined staging ----------
// mode 4 (fused QKV, 768 blocks): col block 0->Q(x0.125*log2e) o0 [B,H,S,64], 1->K o1,
//   2->V o2 [B,H,64,S] (transposed). mode 3 (O-proj, 256 blocks): fp32 out o0, with
//   split-K partial combine on A rows s>=1024 (see load_ctx_row).
__global__ __launch_bounds__(256) void gemm128(const u16* __restrict__ A, const u16* __restrict__ BT,
                                               const float* __restrict__ bias0, const float* __restrict__ bias1,
                                               const float* __restrict__ bias2,
                                               void* __restrict__ o0, void* __restrict__ o1, void* __restrict__ o2,
                                               int mode,
                                               const u16* __restrict__ Op1h, const u16* __restrict__ Op2h,
                                               const float* __restrict__ lp1, const float* __restrict__ lp2) {
  __shared__ __align__(16) u16 Als[128 * 64];  // 16 KB
  __shared__ __align__(16) u16 Bls[128 * 64];  // 16 KB
  int g = blockIdx.x, m0t, n0t;
  if (mode == 4) {  // 768 blocks: panels of 16 m-tiles x 24 n-tiles
    int mh = g / 384, r = g - mh * 384;
    n0t = r >> 4;
    m0t = mh * 16 + (r & 15);
  } else {          // 256 blocks
    m0t = g & 31;
    n0t = g >> 5;
  }
  const int m0 = m0t * 128, n0 = n0t * 128;
  const int lane = threadIdx.x & 63, wave = threadIdx.x >> 6;
  const int quad = lane >> 4, c = lane & 15;
  const int wm = wave >> 1, wn = wave & 1;

  // staging lanes: 8 rows x 8 chunks(16B) per call; wave covers 32 rows via 4 calls
  const int srow = lane >> 3, schunk = lane & 7;
  int soff[4], dst[4], rrow[4];
  #pragma unroll
  for (int q = 0; q < 4; ++q) {
    int r = wave * 32 + q * 8 + srow;
    soff[q] = r * 1024 + (schunk << 3);                 // linear global
    dst[q]  = r * 64 + ((schunk ^ (r & 7)) << 3);       // XOR-swizzled LDS dest
    rrow[q] = m0 + r;                                   // absolute A row (mode 3)
  }
  const u16* gA = A + (size_t)m0 * 1024;
  const u16* gB = BT + (size_t)n0 * 1024;

  int ar[2][4], br[2][4];
  #pragma unroll
  for (int ko = 0; ko < 2; ++ko) {
    #pragma unroll
    for (int i = 0; i < 4; ++i) {
      int rowa = wm * 64 + i * 16 + c;
      ar[ko][i] = rowa * 64 + (((ko * 4 + quad) ^ (rowa & 7)) << 3);
      int rowb = wn * 64 + i * 16 + c;
      br[ko][i] = rowb * 64 + (((ko * 4 + quad) ^ (rowb & 7)) << 3);
    }
  }

  // prefetch slab 0 into VGPRs
  short8_t ra[4], rb[4];
  if (mode == 3) {
    #pragma unroll
    for (int q = 0; q < 4; ++q) ra[q] = load_ctx_row(A, rrow[q], schunk << 3, Op1h, Op2h, lp1, lp2);
  } else {
    #pragma unroll
    for (int q = 0; q < 4; ++q) ra[q] = *(const short8_t*)(gA + soff[q]);
  }
  #pragma unroll
  for (int q = 0; q < 4; ++q) rb[q] = *(const short8_t*)(gB + soff[q]);

  float4_t acc[4][4] = {};
  for (int k0 = 0; k0 < 1024; k0 += 64) {
    // commit prefetched slab to LDS
    #pragma unroll
    for (int q = 0; q < 4; ++q) *(short8_t*)&Als[dst[q]] = ra[q];
    #pragma unroll
    for (int q = 0; q < 4; ++q) *(short8_t*)&Bls[dst[q]] = rb[q];
    __syncthreads();
    // issue next slab's loads now; latency hides under the 32 MFMAs below
    if (k0 < 960) {
      if (mode == 3) {
        #pragma unroll
        for (int q = 0; q < 4; ++q)
          ra[q] = load_ctx_row(A, rrow[q], k0 + 64 + (schunk << 3), Op1h, Op2h, lp1, lp2);
      } else {
        #pragma unroll
        for (int q = 0; q < 4; ++q) ra[q] = *(const short8_t*)(gA + soff[q] + k0 + 64);
      }
      #pragma unroll
      for (int q = 0; q < 4; ++q) rb[q] = *(const short8_t*)(gB + soff[q] + k0 + 64);
    }
    #pragma unroll
    for (int ko = 0; ko < 2; ++ko) {
      short8_t af[4], bfr[4];
      #pragma unroll
      for (int i = 0; i < 4; ++i) af[i] = *(const short8_t*)&Als[ar[ko][i]];
      #pragma unroll
      for (int j = 0; j < 4; ++j) bfr[j] = *(const short8_t*)&Bls[br[ko][j]];
      #pragma unroll
      for (int i = 0; i < 4; ++i)
        #pragma unroll
        for (int j = 0; j < 4; ++j)
          acc[i][j] = __builtin_amdgcn_mfma_f32_16x16x32_bf16(af[i], bfr[j], acc[i][j], 0, 0, 0);
    }
    __syncthreads();  // all reads done before next commit (single LDS buffer)
  }

  const int mrow = m0 + wm * 64, ncol = n0 + wn * 64;
  if (mode == 3) {
    float* o = (float*)o0;
    #pragma unroll
    for (int i = 0; i < 4; ++i) {
      #pragma unroll
      for (int j = 0; j < 4; ++j) {
        int colb = ncol + j * 16 + c;
        float bv = bias0[colb];
        int rowb = mrow + i * 16 + quad * 4;
        #pragma unroll
        for (int r = 0; r < 4; ++r)
          o[(size_t)(rowb + r) * 1024 + colb] = acc[i][j][r] + bv;
      }
    }
  } else {
    #pragma unroll
    for (int j = 0; j < 4; ++j) {
      int colb = ncol + j * 16 + c;     // 0..3071
      int which = colb >> 10;           // 0:Q 1:K 2:V (uniform per j)
      int n1 = colb & 1023, h = n1 >> 6, d = n1 & 63;
      const float* bp = (which == 0) ? bias0 : (which == 1 ? bias1 : bias2);
      float bv = bp[n1];
      #pragma unroll
      for (int i = 0; i < 4; ++i) {
        int rowb = mrow + i * 16 + quad * 4;
        int b = rowb >> 11, s = rowb & 2047;
        if (which == 2) {
          u16* o = (u16*)o2 + (((size_t)(b * 16 + h) * 64 + d) * 2048 + s);
          union { u32 u[2]; u64 ll; } ov;
          ov.u[0] = pk2(acc[i][j][0] + bv, acc[i][j][1] + bv);
          ov.u[1] = pk2(acc[i][j][2] + bv, acc[i][j][3] + bv);
          *(u64*)o = ov.ll;
        } else {
          // Q pre-scale folds softmax's LOG2E: 0.125 * 1.4426950408889634
          float sc = (which == 0) ? 0.18033688011112042f : 1.0f;
          u16* o = (u16*)((which == 0) ? o0 : o1);
          #pragma unroll
          for (int r = 0; r < 4; ++r)
            o[(((size_t)(b * 16 + h) * 2048 + (s + r)) << 6) + d] = f2bf((acc[i][j][r] + bv) * sc);
        }
      }
    }
  }
}

// P^T C-layout -> 16x16x32 B-operand layout via gfx950 permlane swaps (VALU pipe).
__device__ inline short8_t p_to_b_swap(const float* p) {
  u32 a0 = pk2(p[0], p[1]), a1 = pk2(p[2], p[3]);
  u32 b0 = pk2(p[4], p[5]), b1 = pk2(p[6], p[7]);
  asm("v_permlane32_swap_b32 %0, %1" : "+v"(a0), "+v"(b0));
  asm("v_permlane32_swap_b32 %0, %1" : "+v"(a1), "+v"(b1));
  asm("v_permlane16_swap_b32 %0, %1" : "+v"(a0), "+v"(b0));
  asm("v_permlane16_swap_b32 %0, %1" : "+v"(a1), "+v"(b1));
  union { u32 u[4]; short8_t v; } pf;
  pf.u[0] = a0; pf.u[1] = a1; pf.u[2] = b0; pf.u[3] = b1;
  return pf.v;
}

// ---------- flash attention v7: equal-duration split-K workers ----------
// Q,K: [B,H,S,64] bf16 (Q pre-scaled 0.125*log2e); VT: [B,H,64,S]; ctx: [B,S,1024] bf16.
// r3/r6 post-mortem: occupancy pinned at 27% because co-resident heavy+light blocks
// decay to 1-2 blocks/CU (pairing equalizes totals, not concurrency). Fix: 1024
// workers of EXACTLY 16 or 17 key-tiles each -> 4 blocks/CU resident the whole kernel.
// Per bh, pair j: a=31-j (32-j tiles), b=j (j+1 tiles), 33 total.
//   worker A (wid>=16): a keys [0,16)            -> fp16 partial (O,l) slot1
//   worker B (wid<16):  a keys [16,32-j) + all b -> fp16 partial slot2 + bf16 ctx for b
// Fixed-base softmax => partials combine by ADDITION; the O-proj GEMM combines
// (O1+O2)/(l1+l2) for rows s>=1024 during A-staging (no atomics, no extra kernel).
// Partials live in the DEAD Xb/WqkvT workspace regions (no new ws requirement).
// Keeps: K+V LDS dbuf + VGPR prefetch, permlane P-transform, l-via-ones-MFMA,
// all-ones mask fast path, setprio around MFMA clusters.
__global__ __launch_bounds__(256, 4) void attn_kernel(const u16* __restrict__ Q, const u16* __restrict__ K,
                                                      const u16* __restrict__ VT, const float* __restrict__ mask,
                                                      const u32* __restrict__ flags, u16* __restrict__ ctx,
                                                      u16* __restrict__ Op1h, u16* __restrict__ Op2h,
                                                      float* __restrict__ lp1, float* __restrict__ lp2) {
  __shared__ __align__(16) u16 Kls[2 * 64 * 64];  // 2 x 8 KB, [key][d] swizzled
  __shared__ __align__(16) u16 Vls[2 * 64 * 64];  // 2 x 8 KB, [d][key] swizzled
  const float C1 = 10000.0f * 1.4426950408889634f;
  int w = threadIdx.x >> 6, lane = threadIdx.x & 63;
  int quad = lane >> 4, c = lane & 15;
  int g = blockIdx.x;
  int bh = (g & 7) * 4 + ((g >> 3) & 3);   // XCD L2 affinity (bh fixed per g mod 32)
  int wid = g >> 5;                        // worker id within bh, 0..31
  int j = wid & 15;
  bool isB = (wid < 16);                   // B workers (17 tiles) dispatch first
  int qa = 31 - j;
  int b = bh >> 4, h = bh & 15;
  bool ones = flags && (flags[b] != 0);
  const u16* Kp = K + ((size_t)bh << 17);
  const u16* Vp = VT + ((size_t)bh << 17);
  const float* mp = mask + (b << 11);

  // segment table: {q-tile, key-tile range, epilogue kind 0=bf16 1=partial1 2=partial2}
  int nseg = isB ? 2 : 1;
  int sq[2], slo[2], shi[2], spr[2];
  if (isB) { sq[0] = qa; slo[0] = 16; shi[0] = 32 - j; spr[0] = 2;
             sq[1] = j;  slo[1] = 0;  shi[1] = j + 1;  spr[1] = 0; }
  else     { sq[0] = qa; slo[0] = 0;  shi[0] = 16;     spr[0] = 1;
             sq[1] = 0;  slo[1] = 0;  shi[1] = 0;      spr[1] = 0; }

  // staging: 64 rows x 8 chunks(16B) per tile; wave w covers rows w*16..+15 (2 calls)
  const int srow = lane >> 3, schunk = lane & 7;
  const u16* gK[2]; const u16* gV[2]; int dK[2], dV[2];
  #pragma unroll
  for (int i = 0; i < 2; ++i) {
    int R = w * 16 + i * 8 + srow;           // key row (K) / d row (V)
    gK[i] = Kp + R * 64 + (schunk << 3);                 // linear source
    dK[i] = R * 64 + ((schunk ^ (R & 7)) << 3);          // swizzled dest
    gV[i] = Vp + (size_t)R * 2048 + (schunk << 3);
    dV[i] = R * 64 + ((schunk ^ (R & 7)) << 3);
  }

  // fragment read offsets with matching swizzle
  int koff[4][2];
  #pragma unroll
  for (int kg = 0; kg < 4; ++kg) {
    int r = kg * 16 + c;
    #pragma unroll
    for (int ko = 0; ko < 2; ++ko)
      koff[kg][ko] = r * 64 + (((ko * 4 + quad) ^ (r & 7)) << 3);
  }
  int voff[4][2];
  #pragma unroll
  for (int dblk = 0; dblk < 4; ++dblk) {
    int d = dblk * 16 + c;
    #pragma unroll
    for (int kc = 0; kc < 2; ++kc)
      voff[dblk][kc] = d * 64 + (((kc * 4 + quad) ^ (d & 7)) << 3);
  }

  int ke[8];
  #pragma unroll
  for (int e = 0; e < 8; ++e) ke[e] = ((e >> 2) << 4) + quad * 4 + (e & 3);
  int thr = w * 16 + c;  // causal threshold within the diagonal tile
  union { u32 uu[4]; short8_t v; } onesf;
  onesf.uu[0] = onesf.uu[1] = onesf.uu[2] = onesf.uu[3] = 0x3F803F80u;  // bf16 1.0 x8

  // prime prefetch for the first tile of segment 0
  short8_t kreg[2], vreg[2];
  {
    int kb0 = slo[0] << 6;
    #pragma unroll
    for (int i = 0; i < 2; ++i) {
      kreg[i] = *(const short8_t*)(gK[i] + (size_t)kb0 * 64);
      vreg[i] = *(const short8_t*)(gV[i] + kb0);
    }
  }

  int tt = 0;  // running tile counter for LDS dbuf parity (continues across segments)
  for (int seg = 0; seg < nseg; ++seg) {
    const int qt = sq[seg], klo = slo[seg], khi = shi[seg], par = spr[seg];
    const int q0 = qt * 64 + w * 16;
    const u16* Qp = Q + (((size_t)bh * 2048 + q0 + c) << 6) + quad * 8;
    short8_t qf0 = *(const short8_t*)(Qp);
    short8_t qf1 = *(const short8_t*)(Qp + 32);
    float4_t O[4] = {};
    float4_t l4 = {};  // denominator via ones-MFMA; every row holds l[c]

    for (int t = klo; t < khi; ++t, ++tt) {
      int kb = t << 6;
      int bufo = (tt & 1) << 12;  // 4096 u16 per buffer
      #pragma unroll
      for (int i = 0; i < 2; ++i) *(short8_t*)&Kls[bufo + dK[i]] = kreg[i];
      #pragma unroll
      for (int i = 0; i < 2; ++i) *(short8_t*)&Vls[bufo + dV[i]] = vreg[i];
      __syncthreads();
      // prefetch the NEXT tile (possibly first tile of the next segment)
      int nk = (t + 1 < khi) ? ((t + 1) << 6) : ((seg + 1 < nseg) ? (slo[seg + 1] << 6) : -1);
      if (nk >= 0) {
        #pragma unroll
        for (int i = 0; i < 2; ++i) {
          kreg[i] = *(const short8_t*)(gK[i] + (size_t)nk * 64);
          vreg[i] = *(const short8_t*)(gV[i] + nk);
        }
      }
      // ---- S^T = K_tile @ Q^T (8 MFMA) ----
      float4_t s[4];
      __builtin_amdgcn_s_setprio(1);
      #pragma unroll
      for (int kg = 0; kg < 4; ++kg) {
        short8_t k0 = *(const short8_t*)&Kls[bufo + koff[kg][0]];
        short8_t k1 = *(const short8_t*)&Kls[bufo + koff[kg][1]];
        float4_t a = {};
        a = __builtin_amdgcn_mfma_f32_16x16x32_bf16(k0, qf0, a, 0, 0, 0);
        a = __builtin_amdgcn_mfma_f32_16x16x32_bf16(k1, qf1, a, 0, 0, 0);
        s[kg] = a;
      }
      __builtin_amdgcn_s_setprio(0);
      // ---- mask (skipped on all-ones) + fixed-base softmax + C->B transform ----
      float4_t mpl[4];
      if (!ones) {
        #pragma unroll
        for (int kg = 0; kg < 4; ++kg)
          mpl[kg] = (*(const float4_t*)(mp + kb + kg * 16 + quad * 4) - 1.0f) * C1;
      }
      bool diag = (t == qt);
      short8_t pf[2];
      #pragma unroll
      for (int kc = 0; kc < 2; ++kc) {
        float p[8];
        #pragma unroll
        for (int e = 0; e < 8; ++e) {
          int kg = kc * 2 + (e >> 2);
          p[e] = s[kg][e & 3];                // log2e already folded into Q
          if (!ones) p[e] += mpl[kg][e & 3];
        }
        if (diag) {
          #pragma unroll
          for (int e = 0; e < 8; ++e) {
            int ko2 = kc * 32 + ke[e];
            p[e] = (ko2 > thr) ? -50.0f : p[e];
          }
        }
        #pragma unroll
        for (int e = 0; e < 8; ++e) p[e] = exp2f(p[e]);
        pf[kc] = p_to_b_swap(p);
      }
      // ---- ctx^T += V^T_tile @ P^T (8 MFMA) + l via ones-MFMA (2 MFMA) ----
      __builtin_amdgcn_s_setprio(1);
      #pragma unroll
      for (int dblk = 0; dblk < 4; ++dblk) {
        #pragma unroll
        for (int kc = 0; kc < 2; ++kc) {
          short8_t vf = *(const short8_t*)&Vls[bufo + voff[dblk][kc]];
          O[dblk] = __builtin_amdgcn_mfma_f32_16x16x32_bf16(vf, pf[kc], O[dblk], 0, 0, 0);
        }
      }
      l4 = __builtin_amdgcn_mfma_f32_16x16x32_bf16(onesf.v, pf[0], l4, 0, 0, 0);
      l4 = __builtin_amdgcn_mfma_f32_16x16x32_bf16(onesf.v, pf[1], l4, 0, 0, 0);
      __builtin_amdgcn_s_setprio(0);
      // no trailing barrier: next tile writes the OTHER buffer; its leading barrier
      // orders those writes after every wave's reads of this buffer.
    }

    // ---- segment epilogue ----
    if (par == 0) {
      float rl = 1.0f / l4[0];
      u16* op = ctx + ((size_t)(b * 2048 + q0 + c) * 1024 + h * 64 + quad * 4);
      #pragma unroll
      for (int dblk = 0; dblk < 4; ++dblk) {
        union { u32 uu[2]; u64 ll; } ov;
        ov.uu[0] = pk2(O[dblk][0] * rl, O[dblk][1] * rl);
        ov.uu[1] = pk2(O[dblk][2] * rl, O[dblk][3] * rl);
        *(u64*)(op + dblk * 16) = ov.ll;
      }
    } else {
      u16* Op = (par == 1) ? Op1h : Op2h;
      float* lp = (par == 1) ? lp1 : lp2;
      int slot = (bh << 4) + j;
      int ql = w * 16 + c;
      size_t base = ((size_t)slot * 64 + ql) * 64 + quad * 4;
      #pragma unroll
      for (int dblk = 0; dblk < 4; ++dblk) {
        union { _Float16 hv[4]; u64 ll; } pv;
        #pragma unroll
        for (int r = 0; r < 4; ++r) pv.hv[r] = (_Float16)O[dblk][r];
        *(u64*)(Op + base + dblk * 16) = pv.ll;
      }
      if (quad == 0) lp[slot * 64 + ql] = l4[0];
    }
  }
}

// ---------- launch ----------
extern "C" void kernel_launch(void* const* d_in, const int* in_sizes, int n_in,
                              void* d_out, int out_size, void* d_ws, size_t ws_size,
                              hipStream_t stream) {
  const float* X    = (const float*)d_in[0];
  const float* mask = (const float*)d_in[1];
  const float* Wq   = (const float*)d_in[2];
  const float* bq   = (const float*)d_in[3];
  const float* Wk   = (const float*)d_in[4];
  const float* bk   = (const float*)d_in[5];
  const float* Wv   = (const float*)d_in[6];
  const float* bv   = (const float*)d_in[7];
  const float* Wo   = (const float*)d_in[8];
  const float* bo   = (const float*)d_in[9];

  char* w = (char*)d_ws;
  u16* Xb     = (u16*)(w);                 // 8 MB  [4096,1024] bf16
  u16* WqkvT  = (u16*)(w + (8ull  << 20)); // 6 MB  [3072,1024] bf16 (Q|K|V transposed)
  u16* WoT    = (u16*)(w + (14ull << 20)); // 2 MB  [1024,1024] bf16
  u16* Qb     = (u16*)(w + (16ull << 20)); // 8 MB [B,H,S,64]
  u16* Kb     = (u16*)(w + (24ull << 20)); // 8 MB [B,H,S,64]
  u16* VTb    = (u16*)(w + (32ull << 20)); // 8 MB [B,H,64,S]
  u16* Ctx    = (u16*)(w + (40ull << 20)); // 8 MB [4096,1024]
  u32* flags  = (ws_size >= (48ull << 20) + 8) ? (u32*)(w + (48ull << 20)) : nullptr;
  // split-K partials over DEAD regions (Xb/WqkvT are consumed before attn runs):
  u16*   Op1h = (u16*)(w);                               // 4 MB [512][64][64] fp16
  u16*   Op2h = (u16*)(w + (4ull << 20));                // 4 MB
  float* lp1  = (float*)(w + (8ull << 20));              // 128 KB [512][64] fp32
  float* lp2  = (float*)(w + (8ull << 20) + (256ull << 10));

  prologue<<<flags ? 8194 : 8192, 256, 0, stream>>>(X, Wq, Wk, Wv, Wo, Xb, WqkvT, WoT, mask, flags);
  gemm128<<<768, 256, 0, stream>>>(Xb, WqkvT, bq, bk, bv, Qb, Kb, VTb, 4,
                                   nullptr, nullptr, nullptr, nullptr);
  attn_kernel<<<1024, 256, 0, stream>>>(Qb, Kb, VTb, mask, flags, Ctx, Op1h, Op2h, lp1, lp2);
  gemm128<<<256, 256, 0, stream>>>(Ctx, WoT, bo, bo, bo, d_out, d_out, d_out, 3,
                                   Op1h, Op2h, lp1, lp2);
}

// Round 8
// 195.399 us; speedup vs baseline: 1.0849x; 1.0849x over previous
//
#include <hip/hip_runtime.h>

typedef __attribute__((ext_vector_type(8))) short short8_t;  // 8 bf16 (4 VGPRs)
typedef __attribute__((ext_vector_type(4))) float float4_t;  // MFMA C/D
typedef unsigned short u16;
typedef unsigned int u32;
typedef unsigned long long u64;

// ---------- helpers ----------
__device__ inline u16 f2bf(float x) {
  union { float f; u32 u; } v; v.f = x;
  u32 r = v.u + 0x7FFFu + ((v.u >> 16) & 1u);  // round-to-nearest-even
  return (u16)(r >> 16);
}
#if __has_builtin(__builtin_amdgcn_cvt_pk_bf16_f32)
typedef __attribute__((ext_vector_type(2))) __bf16 bf162_t;
__device__ inline u32 pk2(float a, float b) {   // v_cvt_pk_bf16_f32: low=a, high=b, RNE
  union { bf162_t v; u32 u; } cv;
  cv.v = __builtin_amdgcn_cvt_pk_bf16_f32(a, b);
  return cv.u;
}
#else
__device__ inline u32 pk2(float a, float b) {
  return (u32)f2bf(a) | ((u32)f2bf(b) << 16);
}
#endif

// ---------- fused prologue: X fp32->bf16 (blocks 0..4095), W transposes (4096..8191),
// ---------- per-batch all-ones mask flags (8192..8193, only when flags != null) ----------
__global__ __launch_bounds__(256) void prologue(const float* __restrict__ X,
                                                const float* __restrict__ Wq, const float* __restrict__ Wk,
                                                const float* __restrict__ Wv, const float* __restrict__ Wo,
                                                u16* __restrict__ Xb, u16* __restrict__ WqkvT,
                                                u16* __restrict__ WoT, const float* __restrict__ maskp,
                                                u32* __restrict__ flags) {
  __shared__ float tls[32][33];
  int bid = blockIdx.x;
  if (bid < 4096) {
    int i = bid * 256 + threadIdx.x;  // one float4 per thread
    float4_t x = ((const float4_t*)X)[i];
    union { u32 u[2]; u64 ll; } o;
    o.u[0] = pk2(x[0], x[1]);
    o.u[1] = pk2(x[2], x[3]);
    ((u64*)Xb)[i] = o.ll;
  } else if (bid < 8192) {
    int t = bid - 4096;
    int mat = t >> 10, tile = t & 1023;
    const float* W = (mat == 0) ? Wq : (mat == 1) ? Wk : (mat == 2) ? Wv : Wo;
    u16* WT = (mat < 3) ? WqkvT + ((size_t)mat << 20) : WoT;
    int tx = threadIdx.x & 31, ty = threadIdx.x >> 5;  // 32 x 8
    int c0 = (tile & 31) * 32, r0 = (tile >> 5) * 32;  // r0: k, c0: n
    #pragma unroll
    for (int i = 0; i < 4; ++i)
      tls[ty + i * 8][tx] = W[(r0 + ty + i * 8) * 1024 + c0 + tx];
    __syncthreads();
    #pragma unroll
    for (int i = 0; i < 4; ++i)
      WT[(size_t)(c0 + ty + i * 8) * 1024 + r0 + tx] = f2bf(tls[tx][ty + i * 8]);
  } else {
    // all-ones detection for attention mask, one block per batch
    int b = bid - 8192;
    const float* mb = maskp + (b << 11) + threadIdx.x * 8;
    bool ok = true;
    #pragma unroll
    for (int i = 0; i < 8; ++i) ok &= (mb[i] == 1.0f);
    u64 bal = __ballot(ok);
    int w = threadIdx.x >> 6;
    if ((threadIdx.x & 63) == 0) tls[0][w] = (bal == ~0ull) ? 1.0f : 0.0f;
    __syncthreads();
    if (threadIdx.x == 0)
      flags[b] = (tls[0][0] != 0.0f && tls[0][1] != 0.0f &&
                  tls[0][2] != 0.0f && tls[0][3] != 0.0f) ? 1u : 0u;
  }
}

// ---------- GEMM: 128x128 C-tile, 4 waves each 64x64, BK=64, VGPR-pipelined staging ----------
// (r3-exact: the r7 in-GEMM split-K combine cost +24us by re-reading partials per k0 slab)
// mode 4 (fused QKV, 768 blocks): col block 0->Q(x0.125*log2e) o0 [B,H,S,64], 1->K o1,
//   2->V o2 [B,H,64,S] (transposed). mode 3 (O-proj, 256 blocks): fp32 out o0.
__global__ __launch_bounds__(256) void gemm128(const u16* __restrict__ A, const u16* __restrict__ BT,
                                               const float* __restrict__ bias0, const float* __restrict__ bias1,
                                               const float* __restrict__ bias2,
                                               void* __restrict__ o0, void* __restrict__ o1, void* __restrict__ o2,
                                               int mode) {
  __shared__ __align__(16) u16 Als[128 * 64];  // 16 KB
  __shared__ __align__(16) u16 Bls[128 * 64];  // 16 KB
  int g = blockIdx.x, m0t, n0t;
  if (mode == 4) {  // 768 blocks: panels of 16 m-tiles x 24 n-tiles
    int mh = g / 384, r = g - mh * 384;
    n0t = r >> 4;
    m0t = mh * 16 + (r & 15);
  } else {          // 256 blocks
    m0t = g & 31;
    n0t = g >> 5;
  }
  const int m0 = m0t * 128, n0 = n0t * 128;
  const int lane = threadIdx.x & 63, wave = threadIdx.x >> 6;
  const int quad = lane >> 4, c = lane & 15;
  const int wm = wave >> 1, wn = wave & 1;

  // staging lanes: 8 rows x 8 chunks(16B) per call; wave covers 32 rows via 4 calls
  const int srow = lane >> 3, schunk = lane & 7;
  int soff[4], dst[4];
  #pragma unroll
  for (int q = 0; q < 4; ++q) {
    int r = wave * 32 + q * 8 + srow;
    soff[q] = r * 1024 + (schunk << 3);                 // linear global
    dst[q]  = r * 64 + ((schunk ^ (r & 7)) << 3);       // XOR-swizzled LDS dest
  }
  const u16* gA = A + (size_t)m0 * 1024;
  const u16* gB = BT + (size_t)n0 * 1024;

  int ar[2][4], br[2][4];
  #pragma unroll
  for (int ko = 0; ko < 2; ++ko) {
    #pragma unroll
    for (int i = 0; i < 4; ++i) {
      int rowa = wm * 64 + i * 16 + c;
      ar[ko][i] = rowa * 64 + (((ko * 4 + quad) ^ (rowa & 7)) << 3);
      int rowb = wn * 64 + i * 16 + c;
      br[ko][i] = rowb * 64 + (((ko * 4 + quad) ^ (rowb & 7)) << 3);
    }
  }

  // prefetch slab 0 into VGPRs
  short8_t ra[4], rb[4];
  #pragma unroll
  for (int q = 0; q < 4; ++q) ra[q] = *(const short8_t*)(gA + soff[q]);
  #pragma unroll
  for (int q = 0; q < 4; ++q) rb[q] = *(const short8_t*)(gB + soff[q]);

  float4_t acc[4][4] = {};
  for (int k0 = 0; k0 < 1024; k0 += 64) {
    // commit prefetched slab to LDS
    #pragma unroll
    for (int q = 0; q < 4; ++q) *(short8_t*)&Als[dst[q]] = ra[q];
    #pragma unroll
    for (int q = 0; q < 4; ++q) *(short8_t*)&Bls[dst[q]] = rb[q];
    __syncthreads();
    // issue next slab's loads now; latency hides under the 32 MFMAs below
    if (k0 < 960) {
      #pragma unroll
      for (int q = 0; q < 4; ++q) ra[q] = *(const short8_t*)(gA + soff[q] + k0 + 64);
      #pragma unroll
      for (int q = 0; q < 4; ++q) rb[q] = *(const short8_t*)(gB + soff[q] + k0 + 64);
    }
    #pragma unroll
    for (int ko = 0; ko < 2; ++ko) {
      short8_t af[4], bfr[4];
      #pragma unroll
      for (int i = 0; i < 4; ++i) af[i] = *(const short8_t*)&Als[ar[ko][i]];
      #pragma unroll
      for (int j = 0; j < 4; ++j) bfr[j] = *(const short8_t*)&Bls[br[ko][j]];
      #pragma unroll
      for (int i = 0; i < 4; ++i)
        #pragma unroll
        for (int j = 0; j < 4; ++j)
          acc[i][j] = __builtin_amdgcn_mfma_f32_16x16x32_bf16(af[i], bfr[j], acc[i][j], 0, 0, 0);
    }
    __syncthreads();  // all reads done before next commit (single LDS buffer)
  }

  const int mrow = m0 + wm * 64, ncol = n0 + wn * 64;
  if (mode == 3) {
    float* o = (float*)o0;
    #pragma unroll
    for (int i = 0; i < 4; ++i) {
      #pragma unroll
      for (int j = 0; j < 4; ++j) {
        int colb = ncol + j * 16 + c;
        float bv = bias0[colb];
        int rowb = mrow + i * 16 + quad * 4;
        #pragma unroll
        for (int r = 0; r < 4; ++r)
          o[(size_t)(rowb + r) * 1024 + colb] = acc[i][j][r] + bv;
      }
    }
  } else {
    #pragma unroll
    for (int j = 0; j < 4; ++j) {
      int colb = ncol + j * 16 + c;     // 0..3071
      int which = colb >> 10;           // 0:Q 1:K 2:V (uniform per j)
      int n1 = colb & 1023, h = n1 >> 6, d = n1 & 63;
      const float* bp = (which == 0) ? bias0 : (which == 1 ? bias1 : bias2);
      float bv = bp[n1];
      #pragma unroll
      for (int i = 0; i < 4; ++i) {
        int rowb = mrow + i * 16 + quad * 4;
        int b = rowb >> 11, s = rowb & 2047;
        if (which == 2) {
          u16* o = (u16*)o2 + (((size_t)(b * 16 + h) * 64 + d) * 2048 + s);
          union { u32 u[2]; u64 ll; } ov;
          ov.u[0] = pk2(acc[i][j][0] + bv, acc[i][j][1] + bv);
          ov.u[1] = pk2(acc[i][j][2] + bv, acc[i][j][3] + bv);
          *(u64*)o = ov.ll;
        } else {
          // Q pre-scale folds softmax's LOG2E: 0.125 * 1.4426950408889634
          float sc = (which == 0) ? 0.18033688011112042f : 1.0f;
          u16* o = (u16*)((which == 0) ? o0 : o1);
          #pragma unroll
          for (int r = 0; r < 4; ++r)
            o[(((size_t)(b * 16 + h) * 2048 + (s + r)) << 6) + d] = f2bf((acc[i][j][r] + bv) * sc);
        }
      }
    }
  }
}

// P^T C-layout -> 16x16x32 B-operand layout via gfx950 permlane swaps (VALU pipe).
__device__ inline short8_t p_to_b_swap(const float* p) {
  u32 a0 = pk2(p[0], p[1]), a1 = pk2(p[2], p[3]);
  u32 b0 = pk2(p[4], p[5]), b1 = pk2(p[6], p[7]);
  asm("v_permlane32_swap_b32 %0, %1" : "+v"(a0), "+v"(b0));
  asm("v_permlane32_swap_b32 %0, %1" : "+v"(a1), "+v"(b1));
  asm("v_permlane16_swap_b32 %0, %1" : "+v"(a0), "+v"(b0));
  asm("v_permlane16_swap_b32 %0, %1" : "+v"(a1), "+v"(b1));
  union { u32 u[4]; short8_t v; } pf;
  pf.u[0] = a0; pf.u[1] = a1; pf.u[2] = b0; pf.u[3] = b1;
  return pf.v;
}

// softmax for one 16-query half: s[4] (+ mask) -> exp2 -> B-operand fragments pf[2]
__device__ inline void softmax_half(const float4_t* s, const float4_t* mpl, bool ones,
                                    bool diag, int thr, int kb, const int* ke, short8_t* pf) {
  #pragma unroll
  for (int kc = 0; kc < 2; ++kc) {
    float p[8];
    #pragma unroll
    for (int e = 0; e < 8; ++e) {
      int kg = kc * 2 + (e >> 2);
      p[e] = s[kg][e & 3];                // log2e already folded into Q
      if (!ones) p[e] += mpl[kg][e & 3];
    }
    if (diag) {
      #pragma unroll
      for (int e = 0; e < 8; ++e) {
        int keyg = kb + kc * 32 + ke[e];  // global key index
        p[e] = (keyg > thr) ? -50.0f : p[e];
      }
    }
    #pragma unroll
    for (int e = 0; e < 8; ++e) p[e] = exp2f(p[e]);
    pf[kc] = p_to_b_swap(p);
  }
}

// ---------- flash attention v8: 32 queries per wave (LDS amortization) ----------
// Q,K: [B,H,S,64] bf16 (Q pre-scaled 0.125*log2e); VT: [B,H,64,S]; ctx: [B,S,1024] bf16.
// r3/r6/r7 model: wall ~= tile-iters/CU x ~1700cyc chain, TLP-insensitive; the chain's
// shared cost is 20 ds_*_b128 per wave-tile serving only 16 queries. Fix: each wave
// computes 32 queries (two Q fragment pairs). The SAME 8 K-frag + 8 V-frag ds_reads
// feed 32 MFMAs (was 16) and mask loads are key-indexed (shared by both halves) ->
// LDS ops and staging per query HALVE; tile-iters/CU drop 66 -> 34.
// Grid 512 x 256 thr: block = (bh, 128-q tile), 4 waves x 32q. Heavy-first pairing:
// qt = u<8 ? 15-u : u-8, pairs (g,g+256) sum to 34 tiles/CU. Fully-masked tiles
// (kb > q0+31) skip compute on a wave-uniform branch (staging+barrier only).
// __launch_bounds__(256,2): 256-reg budget, live set ~145 regs -> NO spill (r1/r5 trap);
// grid limits residency to 2 blocks/CU anyway. Keeps: K+V LDS dbuf + VGPR prefetch,
// permlane P-transform, l-via-ones-MFMA, mask fast path, setprio.
__global__ __launch_bounds__(256, 2) void attn_kernel(const u16* __restrict__ Q, const u16* __restrict__ K,
                                                      const u16* __restrict__ VT, const float* __restrict__ mask,
                                                      const u32* __restrict__ flags, u16* __restrict__ ctx) {
  __shared__ __align__(16) u16 Kls[2 * 64 * 64];  // 2 x 8 KB, [key][d] swizzled
  __shared__ __align__(16) u16 Vls[2 * 64 * 64];  // 2 x 8 KB, [d][key] swizzled
  const float C1 = 10000.0f * 1.4426950408889634f;
  int w = threadIdx.x >> 6, lane = threadIdx.x & 63;
  int quad = lane >> 4, c = lane & 15;
  int g = blockIdx.x;
  int bh = (g & 7) * 4 + ((g >> 3) & 3);   // XCD L2 affinity
  int u = g >> 5;                          // 0..15
  int qt = (u < 8) ? (15 - u) : (u - 8);   // 128-q tile; heavy first
  int b = bh >> 4, h = bh & 15;
  bool ones = flags && (flags[b] != 0);
  const u16* Kp = K + ((size_t)bh << 17);
  const u16* Vp = VT + ((size_t)bh << 17);
  const float* mp = mask + (b << 11);
  int q0 = qt * 128 + w * 32;              // this wave's first query
  int nt = 2 * qt + 2;                     // key tiles for the block

  // Q^T B-operand fragments: half A = queries q0+c, half B = queries q0+16+c
  const u16* Qp = Q + (((size_t)bh * 2048 + q0 + c) << 6) + quad * 8;
  short8_t qa0 = *(const short8_t*)(Qp);
  short8_t qa1 = *(const short8_t*)(Qp + 32);
  short8_t qb0 = *(const short8_t*)(Qp + (16 << 6));
  short8_t qb1 = *(const short8_t*)(Qp + (16 << 6) + 32);

  // staging: 64 rows x 8 chunks(16B) per tile; wave w covers rows w*16..+15 (2 calls)
  const int srow = lane >> 3, schunk = lane & 7;
  const u16* gK[2]; const u16* gV[2]; int dK[2], dV[2];
  #pragma unroll
  for (int i = 0; i < 2; ++i) {
    int R = w * 16 + i * 8 + srow;           // key row (K) / d row (V)
    gK[i] = Kp + R * 64 + (schunk << 3);                 // linear source
    dK[i] = R * 64 + ((schunk ^ (R & 7)) << 3);          // swizzled dest
    gV[i] = Vp + (size_t)R * 2048 + (schunk << 3);
    dV[i] = R * 64 + ((schunk ^ (R & 7)) << 3);
  }

  // fragment read offsets with matching swizzle
  int koff[4][2];
  #pragma unroll
  for (int kg = 0; kg < 4; ++kg) {
    int r = kg * 16 + c;
    #pragma unroll
    for (int ko = 0; ko < 2; ++ko)
      koff[kg][ko] = r * 64 + (((ko * 4 + quad) ^ (r & 7)) << 3);
  }
  int voff[4][2];
  #pragma unroll
  for (int dblk = 0; dblk < 4; ++dblk) {
    int d = dblk * 16 + c;
    #pragma unroll
    for (int kc = 0; kc < 2; ++kc)
      voff[dblk][kc] = d * 64 + (((kc * 4 + quad) ^ (d & 7)) << 3);
  }

  int ke[8];
  #pragma unroll
  for (int e = 0; e < 8; ++e) ke[e] = ((e >> 2) << 4) + quad * 4 + (e & 3);
  int thrA = q0 + c;        // global causal thresholds
  int thrB = q0 + 16 + c;
  union { u32 uu[4]; short8_t v; } onesf;
  onesf.uu[0] = onesf.uu[1] = onesf.uu[2] = onesf.uu[3] = 0x3F803F80u;  // bf16 1.0 x8

  float4_t OA[4] = {}, OB[4] = {};
  float4_t lA = {}, lB = {};  // denominators via ones-MFMA

  // prefetch tile 0 into VGPRs
  short8_t kreg[2], vreg[2];
  #pragma unroll
  for (int i = 0; i < 2; ++i) { kreg[i] = *(const short8_t*)(gK[i]); vreg[i] = *(const short8_t*)(gV[i]); }

  for (int t = 0; t < nt; ++t) {
    int kb = t << 6;
    int bufo = (t & 1) << 12;  // 4096 u16 per buffer
    #pragma unroll
    for (int i = 0; i < 2; ++i) *(short8_t*)&Kls[bufo + dK[i]] = kreg[i];
    #pragma unroll
    for (int i = 0; i < 2; ++i) *(short8_t*)&Vls[bufo + dV[i]] = vreg[i];
    __syncthreads();
    if (t < nt - 1) {  // issue tile t+1 loads; land during this tile's compute
      int kb2 = (t + 1) << 6;
      #pragma unroll
      for (int i = 0; i < 2; ++i) {
        kreg[i] = *(const short8_t*)(gK[i] + (size_t)kb2 * 64);
        vreg[i] = *(const short8_t*)(gV[i] + kb2);
      }
    }
    if (kb > q0 + 31) continue;  // tile fully masked for this wave (uniform branch)

    // ---- S^T = K_tile @ Q^T for both halves (16 MFMA; K frags read ONCE) ----
    float4_t sA[4], sB[4];
    __builtin_amdgcn_s_setprio(1);
    #pragma unroll
    for (int kg = 0; kg < 4; ++kg) {
      short8_t k0 = *(const short8_t*)&Kls[bufo + koff[kg][0]];
      short8_t k1 = *(const short8_t*)&Kls[bufo + koff[kg][1]];
      float4_t a = {};
      a = __builtin_amdgcn_mfma_f32_16x16x32_bf16(k0, qa0, a, 0, 0, 0);
      a = __builtin_amdgcn_mfma_f32_16x16x32_bf16(k1, qa1, a, 0, 0, 0);
      sA[kg] = a;
      float4_t bb = {};
      bb = __builtin_amdgcn_mfma_f32_16x16x32_bf16(k0, qb0, bb, 0, 0, 0);
      bb = __builtin_amdgcn_mfma_f32_16x16x32_bf16(k1, qb1, bb, 0, 0, 0);
      sB[kg] = bb;
    }
    __builtin_amdgcn_s_setprio(0);
    // ---- mask (key-indexed: shared by both halves; skipped on all-ones) ----
    float4_t mpl[4];
    if (!ones) {
      #pragma unroll
      for (int kg = 0; kg < 4; ++kg)
        mpl[kg] = (*(const float4_t*)(mp + kb + kg * 16 + quad * 4) - 1.0f) * C1;
    }
    bool diag = (kb + 63 > q0);
    short8_t pfA[2], pfB[2];
    softmax_half(sA, mpl, ones, diag, thrA, kb, ke, pfA);
    softmax_half(sB, mpl, ones, diag, thrB, kb, ke, pfB);
    // ---- ctx^T += V^T_tile @ P^T both halves (16 MFMA; V frags read ONCE) + l (4 MFMA) ----
    __builtin_amdgcn_s_setprio(1);
    #pragma unroll
    for (int dblk = 0; dblk < 4; ++dblk) {
      short8_t vf0 = *(const short8_t*)&Vls[bufo + voff[dblk][0]];
      short8_t vf1 = *(const short8_t*)&Vls[bufo + voff[dblk][1]];
      OA[dblk] = __builtin_amdgcn_mfma_f32_16x16x32_bf16(vf0, pfA[0], OA[dblk], 0, 0, 0);
      OA[dblk] = __builtin_amdgcn_mfma_f32_16x16x32_bf16(vf1, pfA[1], OA[dblk], 0, 0, 0);
      OB[dblk] = __builtin_amdgcn_mfma_f32_16x16x32_bf16(vf0, pfB[0], OB[dblk], 0, 0, 0);
      OB[dblk] = __builtin_amdgcn_mfma_f32_16x16x32_bf16(vf1, pfB[1], OB[dblk], 0, 0, 0);
    }
    lA = __builtin_amdgcn_mfma_f32_16x16x32_bf16(onesf.v, pfA[0], lA, 0, 0, 0);
    lA = __builtin_amdgcn_mfma_f32_16x16x32_bf16(onesf.v, pfA[1], lA, 0, 0, 0);
    lB = __builtin_amdgcn_mfma_f32_16x16x32_bf16(onesf.v, pfB[0], lB, 0, 0, 0);
    lB = __builtin_amdgcn_mfma_f32_16x16x32_bf16(onesf.v, pfB[1], lB, 0, 0, 0);
    __builtin_amdgcn_s_setprio(0);
    // no trailing barrier: next tile writes the OTHER buffer; its leading barrier
    // orders those writes after every wave's reads of this buffer.
  }
  // ---- epilogue: l ready in every row of lA/lB; normalize, store both halves ----
  float rlA = 1.0f / lA[0];
  u16* opA = ctx + ((size_t)(b * 2048 + q0 + c) * 1024 + h * 64 + quad * 4);
  #pragma unroll
  for (int dblk = 0; dblk < 4; ++dblk) {
    union { u32 uu[2]; u64 ll; } ov;
    ov.uu[0] = pk2(OA[dblk][0] * rlA, OA[dblk][1] * rlA);
    ov.uu[1] = pk2(OA[dblk][2] * rlA, OA[dblk][3] * rlA);
    *(u64*)(opA + dblk * 16) = ov.ll;
  }
  float rlB = 1.0f / lB[0];
  u16* opB = ctx + ((size_t)(b * 2048 + q0 + 16 + c) * 1024 + h * 64 + quad * 4);
  #pragma unroll
  for (int dblk = 0; dblk < 4; ++dblk) {
    union { u32 uu[2]; u64 ll; } ov;
    ov.uu[0] = pk2(OB[dblk][0] * rlB, OB[dblk][1] * rlB);
    ov.uu[1] = pk2(OB[dblk][2] * rlB, OB[dblk][3] * rlB);
    *(u64*)(opB + dblk * 16) = ov.ll;
  }
}

// ---------- launch ----------
extern "C" void kernel_launch(void* const* d_in, const int* in_sizes, int n_in,
                              void* d_out, int out_size, void* d_ws, size_t ws_size,
                              hipStream_t stream) {
  const float* X    = (const float*)d_in[0];
  const float* mask = (const float*)d_in[1];
  const float* Wq   = (const float*)d_in[2];
  const float* bq   = (const float*)d_in[3];
  const float* Wk   = (const float*)d_in[4];
  const float* bk   = (const float*)d_in[5];
  const float* Wv   = (const float*)d_in[6];
  const float* bv   = (const float*)d_in[7];
  const float* Wo   = (const float*)d_in[8];
  const float* bo   = (const float*)d_in[9];

  char* w = (char*)d_ws;
  u16* Xb     = (u16*)(w);                 // 8 MB  [4096,1024] bf16
  u16* WqkvT  = (u16*)(w + (8ull  << 20)); // 6 MB  [3072,1024] bf16 (Q|K|V transposed)
  u16* WoT    = (u16*)(w + (14ull << 20)); // 2 MB  [1024,1024] bf16
  u16* Qb     = (u16*)(w + (16ull << 20)); // 8 MB [B,H,S,64]
  u16* Kb     = (u16*)(w + (24ull << 20)); // 8 MB [B,H,S,64]
  u16* VTb    = (u16*)(w + (32ull << 20)); // 8 MB [B,H,64,S]
  u16* Ctx    = (u16*)(w + (40ull << 20)); // 8 MB [4096,1024]
  u32* flags  = (ws_size >= (48ull << 20) + 8) ? (u32*)(w + (48ull << 20)) : nullptr;

  prologue<<<flags ? 8194 : 8192, 256, 0, stream>>>(X, Wq, Wk, Wv, Wo, Xb, WqkvT, WoT, mask, flags);
  gemm128<<<768, 256, 0, stream>>>(Xb, WqkvT, bq, bk, bv, Qb, Kb, VTb, 4);
  attn_kernel<<<512, 256, 0, stream>>>(Qb, Kb, VTb, mask, flags, Ctx);
  gemm128<<<256, 256, 0, stream>>>(Ctx, WoT, bo, bo, bo, d_out, d_out, d_out, 3);
}